// Round 3
// baseline (186.743 us; speedup 1.0000x reference)
//
#include <hip/hip_runtime.h>
#include <hip/hip_bf16.h>

using f32x4  = __attribute__((ext_vector_type(4))) float;
using bf16x8 = __attribute__((ext_vector_type(8))) short;
using s16x4  = __attribute__((ext_vector_type(4))) short;

constexpr int kB  = 8;
constexpr int kA  = 32;
constexpr int kT  = 64;
constexpr int kNH = 256;
constexpr int kNE = 256;                 // NEMB
constexpr int kE  = kA * (kA - 1);       // 992
constexpr int kM  = kB * kA * kT;        // 16384 rows of h
constexpr int kK  = kNH;                 // 256
constexpr int kN  = 2 * kNE;             // 512 (Ps | Pr)

__device__ __forceinline__ unsigned short rne_bf16(float f) {
    unsigned int u = __float_as_uint(f);
    u += 0x7fffu + ((u >> 16) & 1u);
    return (unsigned short)(u >> 16);
}
__device__ __forceinline__ float bf16_f32(unsigned short h) {
    return __uint_as_float(((unsigned int)h) << 16);
}
// 3-way split: x ~= hi + mid + lo (each bf16), residual ~2^-21 |x|
__device__ __forceinline__ void split3(float x, unsigned short& h, unsigned short& m,
                                       unsigned short& l) {
    h = rne_bf16(x);
    float r1 = x - bf16_f32(h);
    m = rne_bf16(r1);
    float r2 = r1 - bf16_f32(m);
    l = rne_bf16(r2);
}

// ---- h (f32) -> Ah/Am/Al bf16, 4 elems/thread ----------------------------
__global__ __launch_bounds__(256) void k_split_h(const float* __restrict__ src,
                                                 unsigned short* __restrict__ d1,
                                                 unsigned short* __restrict__ d2,
                                                 unsigned short* __restrict__ d3) {
    int idx = blockIdx.x * 256 + threadIdx.x;           // per 4 elements
    f32x4 v = ((const f32x4*)src)[idx];
    s16x4 o1, o2, o3;
#pragma unroll
    for (int j = 0; j < 4; ++j) {
        unsigned short h, m, l;
        split3(v[j], h, m, l);
        o1[j] = (short)h; o2[j] = (short)m; o3[j] = (short)l;
    }
    *(s16x4*)(d1 + (size_t)idx * 4) = o1;
    *(s16x4*)(d2 + (size_t)idx * 4) = o2;
    *(s16x4*)(d3 + (size_t)idx * 4) = o3;
}

// ---- W (f32 [256][512]) -> Bcat hi/mid/lo bf16 [512][256] (B^T form) -----
__global__ __launch_bounds__(256) void k_split_w(const float* __restrict__ W,
                                                 unsigned short* __restrict__ d1,
                                                 unsigned short* __restrict__ d2,
                                                 unsigned short* __restrict__ d3) {
    int idx = blockIdx.x * 256 + threadIdx.x;           // per 4 elems; 32768 total
    int n  = idx >> 6;                                  // 0..511
    int k4 = (idx & 63) << 2;                           // 0..252
    const float* s = (n < kNE) ? (W + (size_t)n * (2 * kNH) + k4)
                               : (W + (size_t)(n - kNE) * (2 * kNH) + kNH + k4);
    f32x4 v = *(const f32x4*)s;
    s16x4 o1, o2, o3;
#pragma unroll
    for (int j = 0; j < 4; ++j) {
        unsigned short h, m, l;
        split3(v[j], h, m, l);
        o1[j] = (short)h; o2[j] = (short)m; o3[j] = (short)l;
    }
    size_t off = (size_t)n * kK + k4;
    *(s16x4*)(d1 + off) = o1;
    *(s16x4*)(d2 + off) = o2;
    *(s16x4*)(d3 + off) = o3;
}

// ---- derive send/recv atom index per edge from the one-hot selectors -----
__global__ void k_edge_idx(const float* __restrict__ rel_rec,
                           const float* __restrict__ rel_send,
                           int* __restrict__ idx_r, int* __restrict__ idx_s) {
    int e = blockIdx.x * 256 + threadIdx.x;
    if (e >= kE) return;
    int ir = 0, is = 0;
    for (int a = 0; a < kA; ++a) {
        if (rel_rec[(size_t)e * kA + a]  > 0.5f) ir = a;
        if (rel_send[(size_t)e * kA + a] > 0.5f) is = a;
    }
    idx_r[e] = ir;
    idx_s[e] = is;
}

// ---- GEMM: P[16384][512] = A[16384][256] * Bcat[512][256]^T, split-f32 ---
// 128x128 tile, BK=32 (64B rows), 4 waves (2x2), 6 MFMA terms per frag pair:
//   ah*bh + ah*bm + am*bh + ah*bl + al*bh + am*bm   (residual ~2^-21)
// Swizzle: XOR byte-col with (row&3)<<4 — confined to the 64-byte row
// (round-2 bug: (row&7)<<4 escaped the row -> OOB LDS reads -> NaN).
// Applied to BOTH the pre-swizzled global source and the ds_read address
// (rule #21 involution), with linear global_load_lds destinations.
#define GLL(g, l) __builtin_amdgcn_global_load_lds( \
    (const __attribute__((address_space(1))) void*)(g), \
    (__attribute__((address_space(3))) void*)(l), 16, 0, 0)

__global__ __launch_bounds__(256) void k_gemm3(const unsigned short* __restrict__ Ah,
                                               const unsigned short* __restrict__ Am,
                                               const unsigned short* __restrict__ Al,
                                               const unsigned short* __restrict__ Bh,
                                               const unsigned short* __restrict__ Bm,
                                               const unsigned short* __restrict__ Bl,
                                               float* __restrict__ P) {
    __shared__ unsigned short sAh[128 * 32], sAm[128 * 32], sAl[128 * 32];
    __shared__ unsigned short sBh[128 * 32], sBm[128 * 32], sBl[128 * 32];
    const int tid  = threadIdx.x;
    const int lane = tid & 63;
    const int wave = tid >> 6;
    const int wr = wave >> 1, wc = wave & 1;
    const int bm = blockIdx.x, bn = blockIdx.y;

    // staging: thread tid covers LDS bytes [tid*16, tid*16+16) of a 64-row half-tile
    const int sr   = tid >> 2;               // row within half-tile (0..63)
    const int scb  = (tid & 3) << 4;         // byte col within 64B row
    const int scbs = scb ^ ((sr & 3) << 4);  // pre-swizzled source byte col, in [0,64)
    const size_t rA  = (size_t)(bm * 128 + sr) * kK + (scbs >> 1);
    const size_t rB  = (size_t)(bn * 128 + sr) * kK + (scbs >> 1);
    const size_t rA1 = rA + (size_t)64 * kK;
    const size_t rB1 = rB + (size_t)64 * kK;
    const int l0 = tid * 8, l1 = 64 * 32 + tid * 8;

    const int fr  = lane & 15;               // row within 16-row fragment
    const int fkb = (lane >> 4) << 4;        // byte col of k-slice (0/16/32/48)

    f32x4 acc[4][4] = {};

    for (int kt = 0; kt < kK / 32; ++kt) {
        const int kk = kt * 32;              // element offset along K
        __syncthreads();
        GLL(Ah + rA + kk, sAh + l0);  GLL(Ah + rA1 + kk, sAh + l1);
        GLL(Am + rA + kk, sAm + l0);  GLL(Am + rA1 + kk, sAm + l1);
        GLL(Al + rA + kk, sAl + l0);  GLL(Al + rA1 + kk, sAl + l1);
        GLL(Bh + rB + kk, sBh + l0);  GLL(Bh + rB1 + kk, sBh + l1);
        GLL(Bm + rB + kk, sBm + l0);  GLL(Bm + rB1 + kk, sBm + l1);
        GLL(Bl + rB + kk, sBl + l0);  GLL(Bl + rB1 + kk, sBl + l1);
        __syncthreads();

        bf16x8 ah[4], am[4], al[4], bh[4], bmf[4], bl[4];
#pragma unroll
        for (int mi = 0; mi < 4; ++mi) {
            int row = wr * 64 + mi * 16 + fr;
            int off = row * 64 + (fkb ^ ((row & 3) << 4));   // in [0, 8192)
            ah[mi] = *(const bf16x8*)((const char*)sAh + off);
            am[mi] = *(const bf16x8*)((const char*)sAm + off);
            al[mi] = *(const bf16x8*)((const char*)sAl + off);
        }
#pragma unroll
        for (int ni = 0; ni < 4; ++ni) {
            int row = wc * 64 + ni * 16 + fr;
            int off = row * 64 + (fkb ^ ((row & 3) << 4));
            bh[ni]  = *(const bf16x8*)((const char*)sBh + off);
            bmf[ni] = *(const bf16x8*)((const char*)sBm + off);
            bl[ni]  = *(const bf16x8*)((const char*)sBl + off);
        }
#pragma unroll
        for (int mi = 0; mi < 4; ++mi)
#pragma unroll
            for (int ni = 0; ni < 4; ++ni) {
                f32x4 c = acc[mi][ni];
                c = __builtin_amdgcn_mfma_f32_16x16x32_bf16(ah[mi], bh[ni],  c, 0, 0, 0);
                c = __builtin_amdgcn_mfma_f32_16x16x32_bf16(ah[mi], bmf[ni], c, 0, 0, 0);
                c = __builtin_amdgcn_mfma_f32_16x16x32_bf16(am[mi], bh[ni],  c, 0, 0, 0);
                c = __builtin_amdgcn_mfma_f32_16x16x32_bf16(ah[mi], bl[ni],  c, 0, 0, 0);
                c = __builtin_amdgcn_mfma_f32_16x16x32_bf16(al[mi], bh[ni],  c, 0, 0, 0);
                c = __builtin_amdgcn_mfma_f32_16x16x32_bf16(am[mi], bmf[ni], c, 0, 0, 0);
                acc[mi][ni] = c;
            }
    }

    // epilogue: C/D layout col=lane&15, row=(lane>>4)*4+r   [m89-verified]
    const int col = lane & 15;
    const int rb  = (lane >> 4) << 2;
#pragma unroll
    for (int mi = 0; mi < 4; ++mi)
#pragma unroll
        for (int ni = 0; ni < 4; ++ni) {
            int n = bn * 128 + wc * 64 + ni * 16 + col;
#pragma unroll
            for (int r = 0; r < 4; ++r) {
                int m = bm * 128 + wr * 64 + mi * 16 + rb + r;
                P[(size_t)m * kN + n] = acc[mi][ni][r];
            }
        }
}

// ---- gather-add: out[b,e,t,:] = Ps[b,send,t,:] + Pr[b,recv,t,:] + bias ---
// grid = B*E blocks; XCD swizzle maps each batch b to one XCD so P[b] (4MB)
// lives in that XCD's L2.
__global__ __launch_bounds__(256) void k_gather(const float* __restrict__ P,
                                                const float* __restrict__ bias,
                                                const int* __restrict__ idx_s,
                                                const int* __restrict__ idx_r,
                                                float* __restrict__ out) {
    int blk = (blockIdx.x & 7) * kE + (blockIdx.x >> 3);   // 7936 = 8 * 992 exact
    int b = blk / kE;
    int e = blk - b * kE;
    int i = idx_s[e];
    int j = idx_r[e];
    int o4 = threadIdx.x & 63;                 // float4 col 0..63 (256 f32)
    int tq = threadIdx.x >> 6;                 // wave id -> t phase
    const f32x4* Ps = (const f32x4*)(P + (size_t)((b * kA + i) * kT) * kN);
    const f32x4* Pr = (const f32x4*)(P + (size_t)((b * kA + j) * kT) * kN + kNE);
    f32x4 bv = ((const f32x4*)bias)[o4];
    f32x4* ov = (f32x4*)(out + (size_t)blk * (kT * kNE));
    for (int t = tq; t < kT; t += 4) {
        f32x4 a = Ps[t * (kN / 4) + o4];
        f32x4 c = Pr[t * (kN / 4) + o4];
        ov[t * (kNE / 4) + o4] = a + c + bv;
    }
}

extern "C" void kernel_launch(void* const* d_in, const int* in_sizes, int n_in,
                              void* d_out, int out_size, void* d_ws, size_t ws_size,
                              hipStream_t stream) {
    const float* h    = (const float*)d_in[0];
    const float* rrec = (const float*)d_in[1];
    const float* rsnd = (const float*)d_in[2];
    const float* W    = (const float*)d_in[3];
    const float* bias = (const float*)d_in[4];
    float* out = (float*)d_out;

    char* ws = (char*)d_ws;
    const size_t MB = 1024 * 1024;
    unsigned short* Ah = (unsigned short*)(ws);                  // 8 MB
    unsigned short* Am = (unsigned short*)(ws + 8 * MB);         // 8 MB
    unsigned short* Al = (unsigned short*)(ws + 16 * MB);        // 8 MB
    unsigned short* Bh = (unsigned short*)(ws + 24 * MB);        // 256 KB
    unsigned short* Bm = (unsigned short*)(ws + 24 * MB + 256 * 1024);
    unsigned short* Bl = (unsigned short*)(ws + 24 * MB + 512 * 1024);
    float* P  = (float*)(ws + 25 * MB);                          // 32 MB
    int* idxS = (int*)(ws + 57 * MB);
    int* idxR = idxS + 1024;

    k_split_h <<<dim3(kM * kK / (4 * 256)), dim3(256), 0, stream>>>(h, Ah, Am, Al);
    k_split_w <<<dim3(kN * kK / (4 * 256)), dim3(256), 0, stream>>>(W, Bh, Bm, Bl);
    k_edge_idx<<<dim3((kE + 255) / 256),    dim3(256), 0, stream>>>(rrec, rsnd, idxR, idxS);
    k_gemm3   <<<dim3(kM / 128, kN / 128),  dim3(256), 0, stream>>>(Ah, Am, Al, Bh, Bm, Bl, P);
    k_gather  <<<dim3(kB * kE),             dim3(256), 0, stream>>>(P, bias, idxS, idxR, out);
}

// Round 4
// 140.730 us; speedup vs baseline: 1.3270x; 1.3270x over previous
//
#include <hip/hip_runtime.h>
#include <hip/hip_bf16.h>

using f32x4  = __attribute__((ext_vector_type(4))) float;
using bf16x8 = __attribute__((ext_vector_type(8))) short;
using s16x4  = __attribute__((ext_vector_type(4))) short;

constexpr int kB  = 8;
constexpr int kA  = 32;
constexpr int kT  = 64;
constexpr int kNH = 256;
constexpr int kNE = 256;                 // NEMB
constexpr int kE  = kA * (kA - 1);       // 992
constexpr int kM  = kB * kA * kT;        // 16384 rows of h
constexpr int kK  = kNH;                 // 256
constexpr int kN  = 2 * kNE;             // 512 (Ps | Pr)

__device__ __forceinline__ unsigned short rne_bf16(float f) {
    unsigned int u = __float_as_uint(f);
    u += 0x7fffu + ((u >> 16) & 1u);
    return (unsigned short)(u >> 16);
}
__device__ __forceinline__ float bf16_f32(unsigned short h) {
    return __uint_as_float(((unsigned int)h) << 16);
}
// 3-way split: x ~= hi + mid + lo (each bf16), residual ~2^-27 |x|
__device__ __forceinline__ void split3(float x, unsigned short& h, unsigned short& m,
                                       unsigned short& l) {
    h = rne_bf16(x);
    float r1 = x - bf16_f32(h);
    m = rne_bf16(r1);
    float r2 = r1 - bf16_f32(m);
    l = rne_bf16(r2);
}

// ---- h (f32) -> Ah/Am/Al bf16, 4 elems/thread ----------------------------
__global__ __launch_bounds__(256) void k_split_h(const float* __restrict__ src,
                                                 unsigned short* __restrict__ d1,
                                                 unsigned short* __restrict__ d2,
                                                 unsigned short* __restrict__ d3) {
    int idx = blockIdx.x * 256 + threadIdx.x;           // per 4 elements
    f32x4 v = ((const f32x4*)src)[idx];
    s16x4 o1, o2, o3;
#pragma unroll
    for (int j = 0; j < 4; ++j) {
        unsigned short h, m, l;
        split3(v[j], h, m, l);
        o1[j] = (short)h; o2[j] = (short)m; o3[j] = (short)l;
    }
    *(s16x4*)(d1 + (size_t)idx * 4) = o1;
    *(s16x4*)(d2 + (size_t)idx * 4) = o2;
    *(s16x4*)(d3 + (size_t)idx * 4) = o3;
}

// ---- W -> Bcat hi/mid/lo bf16 [512][256] (B^T form) + edge LUT -----------
__global__ __launch_bounds__(256) void k_split_w(const float* __restrict__ W,
                                                 unsigned short* __restrict__ d1,
                                                 unsigned short* __restrict__ d2,
                                                 unsigned short* __restrict__ d3,
                                                 const float* __restrict__ rel_rec,
                                                 const float* __restrict__ rel_send,
                                                 int* __restrict__ ij2e) {
    int idx = blockIdx.x * 256 + threadIdx.x;           // per 4 elems; 32768 total
    int n  = idx >> 6;                                  // 0..511
    int k4 = (idx & 63) << 2;                           // 0..252
    const float* s = (n < kNE) ? (W + (size_t)n * (2 * kNH) + k4)
                               : (W + (size_t)(n - kNE) * (2 * kNH) + kNH + k4);
    f32x4 v = *(const f32x4*)s;
    s16x4 o1, o2, o3;
#pragma unroll
    for (int j = 0; j < 4; ++j) {
        unsigned short h, m, l;
        split3(v[j], h, m, l);
        o1[j] = (short)h; o2[j] = (short)m; o3[j] = (short)l;
    }
    size_t off = (size_t)n * kK + k4;
    *(s16x4*)(d1 + off) = o1;
    *(s16x4*)(d2 + off) = o2;
    *(s16x4*)(d3 + off) = o3;

    // inverse edge LUT: ij2e[send*32 + recv] = e  (first 4 blocks)
    if (blockIdx.x < 4) {
        int e = blockIdx.x * 256 + threadIdx.x;
        if (e < kE) {
            int ir = 0, is = 0;
            for (int a = 0; a < kA; ++a) {
                if (rel_rec[(size_t)e * kA + a]  > 0.5f) ir = a;
                if (rel_send[(size_t)e * kA + a] > 0.5f) is = a;
            }
            ij2e[is * kA + ir] = e;
        }
    }
}

// ---- GEMM: P[16384][512] = A[16384][256] * Bcat[512][256]^T, split-f32 ---
// 128x128 tile, BK=32 (64B rows), 4 waves (2x2), 6 MFMA terms per frag pair:
//   ah*bh + ah*bm + am*bh + ah*bl + al*bh + am*bm   (residual ~2^-27)
// Swizzle: XOR byte-col with ((row>>1)&3)<<4 — in-row (64B), spreads the 8
// same-bank-window rows of a 16-row fragment over all 4 16B slots -> 2-way
// (free) instead of 4-way. Same XOR on pre-swizzled global source (involution).
// Grid is 1-D, remapped so XCD x computes P rows of batch b=x (L2 locality
// for the gather that follows).
#define GLL(g, l) __builtin_amdgcn_global_load_lds( \
    (const __attribute__((address_space(1))) void*)(g), \
    (__attribute__((address_space(3))) void*)(l), 16, 0, 0)

__global__ __launch_bounds__(256) void k_gemm3(const unsigned short* __restrict__ Ah,
                                               const unsigned short* __restrict__ Am,
                                               const unsigned short* __restrict__ Al,
                                               const unsigned short* __restrict__ Bh,
                                               const unsigned short* __restrict__ Bm,
                                               const unsigned short* __restrict__ Bl,
                                               float* __restrict__ P) {
    __shared__ unsigned short sAh[128 * 32], sAm[128 * 32], sAl[128 * 32];
    __shared__ unsigned short sBh[128 * 32], sBm[128 * 32], sBl[128 * 32];
    const int tid  = threadIdx.x;
    const int lane = tid & 63;
    const int wave = tid >> 6;
    const int wr = wave >> 1, wc = wave & 1;
    // XCD-aware decode: bid%8 = XCD -> bm in [16*xcd, 16*xcd+16) -> batch b=xcd
    const int bid = blockIdx.x;                     // 0..511
    const int bm  = (bid & 7) * 16 + ((bid >> 3) & 15);
    const int bn  = bid >> 7;                       // 0..3

    // staging: thread tid covers LDS bytes [tid*16, tid*16+16) of a 64-row half-tile
    const int sr   = tid >> 2;                      // row within half-tile (0..63)
    const int scb  = (tid & 3) << 4;                // byte col within 64B row
    const int scbs = scb ^ (((sr >> 1) & 3) << 4);  // pre-swizzled source col, in [0,64)
    const size_t rA  = (size_t)(bm * 128 + sr) * kK + (scbs >> 1);
    const size_t rB  = (size_t)(bn * 128 + sr) * kK + (scbs >> 1);
    const size_t rA1 = rA + (size_t)64 * kK;
    const size_t rB1 = rB + (size_t)64 * kK;
    const int l0 = tid * 8, l1 = 64 * 32 + tid * 8;

    const int fr  = lane & 15;               // row within 16-row fragment
    const int fkb = (lane >> 4) << 4;        // byte col of k-slice (0/16/32/48)
    const int swz = ((fr >> 1) & 3) << 4;    // row-dependent XOR (row%16 == fr)

    f32x4 acc[4][4] = {};

    for (int kt = 0; kt < kK / 32; ++kt) {
        const int kk = kt * 32;              // element offset along K
        __syncthreads();
        GLL(Ah + rA + kk, sAh + l0);  GLL(Ah + rA1 + kk, sAh + l1);
        GLL(Am + rA + kk, sAm + l0);  GLL(Am + rA1 + kk, sAm + l1);
        GLL(Al + rA + kk, sAl + l0);  GLL(Al + rA1 + kk, sAl + l1);
        GLL(Bh + rB + kk, sBh + l0);  GLL(Bh + rB1 + kk, sBh + l1);
        GLL(Bm + rB + kk, sBm + l0);  GLL(Bm + rB1 + kk, sBm + l1);
        GLL(Bl + rB + kk, sBl + l0);  GLL(Bl + rB1 + kk, sBl + l1);
        __syncthreads();

        bf16x8 ah[4], am[4], al[4], bh[4], bmf[4], bl[4];
#pragma unroll
        for (int mi = 0; mi < 4; ++mi) {
            int row = wr * 64 + mi * 16 + fr;
            int off = row * 64 + (fkb ^ swz);
            ah[mi] = *(const bf16x8*)((const char*)sAh + off);
            am[mi] = *(const bf16x8*)((const char*)sAm + off);
            al[mi] = *(const bf16x8*)((const char*)sAl + off);
        }
#pragma unroll
        for (int ni = 0; ni < 4; ++ni) {
            int row = wc * 64 + ni * 16 + fr;
            int off = row * 64 + (fkb ^ swz);
            bh[ni]  = *(const bf16x8*)((const char*)sBh + off);
            bmf[ni] = *(const bf16x8*)((const char*)sBm + off);
            bl[ni]  = *(const bf16x8*)((const char*)sBl + off);
        }
#pragma unroll
        for (int mi = 0; mi < 4; ++mi)
#pragma unroll
            for (int ni = 0; ni < 4; ++ni) {
                f32x4 c = acc[mi][ni];
                c = __builtin_amdgcn_mfma_f32_16x16x32_bf16(ah[mi], bh[ni],  c, 0, 0, 0);
                c = __builtin_amdgcn_mfma_f32_16x16x32_bf16(ah[mi], bmf[ni], c, 0, 0, 0);
                c = __builtin_amdgcn_mfma_f32_16x16x32_bf16(am[mi], bh[ni],  c, 0, 0, 0);
                c = __builtin_amdgcn_mfma_f32_16x16x32_bf16(ah[mi], bl[ni],  c, 0, 0, 0);
                c = __builtin_amdgcn_mfma_f32_16x16x32_bf16(al[mi], bh[ni],  c, 0, 0, 0);
                c = __builtin_amdgcn_mfma_f32_16x16x32_bf16(am[mi], bmf[ni], c, 0, 0, 0);
                acc[mi][ni] = c;
            }
    }

    // epilogue: C/D layout col=lane&15, row=(lane>>4)*4+r   [m89-verified]
    const int col = lane & 15;
    const int rb  = (lane >> 4) << 2;
#pragma unroll
    for (int mi = 0; mi < 4; ++mi)
#pragma unroll
        for (int ni = 0; ni < 4; ++ni) {
            int n = bn * 128 + wc * 64 + ni * 16 + col;
#pragma unroll
            for (int r = 0; r < 4; ++r) {
                int m = bm * 128 + wr * 64 + mi * 16 + rb + r;
                P[(size_t)m * kN + n] = acc[mi][ni][r];
            }
        }
}

// ---- gather v2: 4x4 atom-group blocking ----------------------------------
// block = (b, gi, gj): 4 senders x 4 receivers = up to 16 edges.
// Per (t, c4): 8 P loads feed 16 output stores (read/write ratio 0.5 vs 2.0).
// b = bid&7 pins each batch's P slice (4MB) to one XCD's L2 (where k_gemm3
// produced it); output uses nontemporal stores so the 520MB write stream
// doesn't evict P from L2.
__global__ __launch_bounds__(256) void k_gather2(const float* __restrict__ P,
                                                 const float* __restrict__ bias,
                                                 const int* __restrict__ ij2e,
                                                 float* __restrict__ out) {
    const int bid = blockIdx.x;              // 0..511
    const int b  = bid & 7;
    const int gi = (bid >> 3) & 7;
    const int gj = bid >> 6;
    __shared__ int se[16];
    if (threadIdx.x < 16) {
        int si = threadIdx.x >> 2, rj = threadIdx.x & 3;
        int i = gi * 4 + si, j = gj * 4 + rj;
        se[threadIdx.x] = (i == j) ? -1 : ij2e[i * kA + j];
    }
    __syncthreads();
    int e[16];
#pragma unroll
    for (int k = 0; k < 16; ++k) e[k] = se[k];

    const int c  = threadIdx.x & 63;         // f32x4 col 0..63
    const int t0 = threadIdx.x >> 6;
    f32x4 bv = ((const f32x4*)bias)[c];
    const float* Pb = P + (size_t)(b * kA) * kT * kN;
    float* outb = out + (size_t)b * kE * kT * kNE;

    for (int t = t0; t < kT; t += 4) {
        f32x4 ps[4], pr[4];
#pragma unroll
        for (int si = 0; si < 4; ++si)
            ps[si] = *(const f32x4*)(Pb + ((size_t)(gi * 4 + si) * kT + t) * kN + c * 4);
#pragma unroll
        for (int rj = 0; rj < 4; ++rj)
            pr[rj] = *(const f32x4*)(Pb + ((size_t)(gj * 4 + rj) * kT + t) * kN + kNE + c * 4);
#pragma unroll
        for (int si = 0; si < 4; ++si)
#pragma unroll
            for (int rj = 0; rj < 4; ++rj) {
                int ee = e[si * 4 + rj];
                if (ee >= 0) {
                    f32x4 v = ps[si] + pr[rj] + bv;
                    __builtin_nontemporal_store(
                        v, (f32x4*)(outb + ((size_t)ee * kT + t) * kNE + c * 4));
                }
            }
    }
}

extern "C" void kernel_launch(void* const* d_in, const int* in_sizes, int n_in,
                              void* d_out, int out_size, void* d_ws, size_t ws_size,
                              hipStream_t stream) {
    const float* h    = (const float*)d_in[0];
    const float* rrec = (const float*)d_in[1];
    const float* rsnd = (const float*)d_in[2];
    const float* W    = (const float*)d_in[3];
    const float* bias = (const float*)d_in[4];
    float* out = (float*)d_out;

    char* ws = (char*)d_ws;
    const size_t MB = 1024 * 1024;
    unsigned short* Ah = (unsigned short*)(ws);                  // 8 MB
    unsigned short* Am = (unsigned short*)(ws + 8 * MB);         // 8 MB
    unsigned short* Al = (unsigned short*)(ws + 16 * MB);        // 8 MB
    unsigned short* Bh = (unsigned short*)(ws + 24 * MB);        // 256 KB
    unsigned short* Bm = (unsigned short*)(ws + 24 * MB + 256 * 1024);
    unsigned short* Bl = (unsigned short*)(ws + 24 * MB + 512 * 1024);
    float* P   = (float*)(ws + 25 * MB);                         // 32 MB
    int* ij2e  = (int*)(ws + 57 * MB);                           // 4 KB

    k_split_h <<<dim3(kM * kK / (4 * 256)), dim3(256), 0, stream>>>(h, Ah, Am, Al);
    k_split_w <<<dim3(kN * kK / (4 * 256)), dim3(256), 0, stream>>>(W, Bh, Bm, Bl,
                                                                    rrec, rsnd, ij2e);
    k_gemm3   <<<dim3(512),                 dim3(256), 0, stream>>>(Ah, Am, Al, Bh, Bm, Bl, P);
    k_gather2 <<<dim3(512),                 dim3(256), 0, stream>>>(P, bias, ij2e, out);
}

// Round 5
// 139.677 us; speedup vs baseline: 1.3370x; 1.0075x over previous
//
#include <hip/hip_runtime.h>
#include <hip/hip_bf16.h>

using f32x4  = __attribute__((ext_vector_type(4))) float;
using bf16x8 = __attribute__((ext_vector_type(8))) short;
using s16x4  = __attribute__((ext_vector_type(4))) short;

constexpr int kB  = 8;
constexpr int kA  = 32;
constexpr int kT  = 64;
constexpr int kNH = 256;
constexpr int kNE = 256;                 // NEMB
constexpr int kE  = kA * (kA - 1);       // 992
constexpr int kM  = kB * kA * kT;        // 16384 rows of h
constexpr int kK  = kNH;                 // 256
constexpr int kN  = 2 * kNE;             // 512 (Ps | Pr)

__device__ __forceinline__ unsigned short rne_bf16(float f) {
    unsigned int u = __float_as_uint(f);
    u += 0x7fffu + ((u >> 16) & 1u);
    return (unsigned short)(u >> 16);
}
__device__ __forceinline__ float bf16_f32(unsigned short h) {
    return __uint_as_float(((unsigned int)h) << 16);
}
// 3-way split: x ~= hi + mid + lo (each bf16), residual ~2^-24 |x|
__device__ __forceinline__ void split3(float x, unsigned short& h, unsigned short& m,
                                       unsigned short& l) {
    h = rne_bf16(x);
    float r1 = x - bf16_f32(h);
    m = rne_bf16(r1);
    float r2 = r1 - bf16_f32(m);
    l = rne_bf16(r2);
}

// ---- fused split: h -> Ah/Am/Al ; W -> Bh/Bm/Bl (B^T form) ; edge LUT ----
__global__ __launch_bounds__(256) void k_split_all(const float* __restrict__ hsrc,
                                                   unsigned short* __restrict__ a1,
                                                   unsigned short* __restrict__ a2,
                                                   unsigned short* __restrict__ a3,
                                                   const float* __restrict__ W,
                                                   unsigned short* __restrict__ b1,
                                                   unsigned short* __restrict__ b2,
                                                   unsigned short* __restrict__ b3,
                                                   const float* __restrict__ rel_rec,
                                                   const float* __restrict__ rel_send,
                                                   int* __restrict__ ij2e) {
    const int bidx = blockIdx.x;
    if (bidx < 4096) {                                  // h: 16384*256 elems / 4
        int idx = bidx * 256 + threadIdx.x;
        f32x4 v = ((const f32x4*)hsrc)[idx];
        s16x4 o1, o2, o3;
#pragma unroll
        for (int j = 0; j < 4; ++j) {
            unsigned short h, m, l;
            split3(v[j], h, m, l);
            o1[j] = (short)h; o2[j] = (short)m; o3[j] = (short)l;
        }
        *(s16x4*)(a1 + (size_t)idx * 4) = o1;
        *(s16x4*)(a2 + (size_t)idx * 4) = o2;
        *(s16x4*)(a3 + (size_t)idx * 4) = o3;
        return;
    }
    const int wb  = bidx - 4096;                        // 0..127
    int idx = wb * 256 + threadIdx.x;                   // per 4 elems; 32768 total
    int n  = idx >> 6;                                  // 0..511
    int k4 = (idx & 63) << 2;                           // 0..252
    const float* s = (n < kNE) ? (W + (size_t)n * (2 * kNH) + k4)
                               : (W + (size_t)(n - kNE) * (2 * kNH) + kNH + k4);
    f32x4 v = *(const f32x4*)s;
    s16x4 o1, o2, o3;
#pragma unroll
    for (int j = 0; j < 4; ++j) {
        unsigned short h, m, l;
        split3(v[j], h, m, l);
        o1[j] = (short)h; o2[j] = (short)m; o3[j] = (short)l;
    }
    size_t off = (size_t)n * kK + k4;
    *(s16x4*)(b1 + off) = o1;
    *(s16x4*)(b2 + off) = o2;
    *(s16x4*)(b3 + off) = o3;

    // inverse edge LUT: ij2e[send*32 + recv] = e  (first 4 W-blocks)
    if (wb < 4) {
        int e = wb * 256 + threadIdx.x;
        if (e < kE) {
            int ir = 0, is = 0;
            for (int a = 0; a < kA; ++a) {
                if (rel_rec[(size_t)e * kA + a]  > 0.5f) ir = a;
                if (rel_send[(size_t)e * kA + a] > 0.5f) is = a;
            }
            ij2e[is * kA + ir] = e;
        }
    }
}

// ---- GEMM: P[16384][512] = A[16384][256] * Bcat[512][256]^T, split-f32 ---
// 128x128 tile, BK=32 (64B rows), 4 waves (2x2), 6 MFMA terms per frag pair:
//   ah*bh + ah*bm + am*bh + ah*bl + al*bh + am*bm   (residual ~2^-24)
// Swizzle: XOR byte-col with ((row>>1)&3)<<4 — in-row (64B), 2-way conflicts
// (free). Same XOR on pre-swizzled global source (involution, rule #21).
// Decode: xcd=bid&7 pins batch b=xcd to its XCD (L2 locality for gather);
// bn=(bid>>3)&3 varies FASTEST within an XCD so the 4 blocks sharing an
// A-panel (576KB) run back-to-back -> A re-reads hit L2 (was 128 apart:
// ~96MB A HBM traffic; now ~24MB).
#define GLL(g, l) __builtin_amdgcn_global_load_lds( \
    (const __attribute__((address_space(1))) void*)(g), \
    (__attribute__((address_space(3))) void*)(l), 16, 0, 0)

__global__ __launch_bounds__(256) void k_gemm3(const unsigned short* __restrict__ Ah,
                                               const unsigned short* __restrict__ Am,
                                               const unsigned short* __restrict__ Al,
                                               const unsigned short* __restrict__ Bh,
                                               const unsigned short* __restrict__ Bm,
                                               const unsigned short* __restrict__ Bl,
                                               float* __restrict__ P) {
    __shared__ unsigned short sAh[128 * 32], sAm[128 * 32], sAl[128 * 32];
    __shared__ unsigned short sBh[128 * 32], sBm[128 * 32], sBl[128 * 32];
    const int tid  = threadIdx.x;
    const int lane = tid & 63;
    const int wave = tid >> 6;
    const int wr = wave >> 1, wc = wave & 1;
    const int bid = blockIdx.x;                     // 0..511
    const int xcd = bid & 7;
    const int idx = bid >> 3;                       // 0..63
    const int bn  = idx & 3;                        // fastest within XCD
    const int bm  = xcd * 16 + (idx >> 2);          // batch b = xcd

    // staging: thread tid covers LDS bytes [tid*16, tid*16+16) of a 64-row half-tile
    const int sr   = tid >> 2;                      // row within half-tile (0..63)
    const int scb  = (tid & 3) << 4;                // byte col within 64B row
    const int scbs = scb ^ (((sr >> 1) & 3) << 4);  // pre-swizzled source col, in [0,64)
    const size_t rA  = (size_t)(bm * 128 + sr) * kK + (scbs >> 1);
    const size_t rB  = (size_t)(bn * 128 + sr) * kK + (scbs >> 1);
    const size_t rA1 = rA + (size_t)64 * kK;
    const size_t rB1 = rB + (size_t)64 * kK;
    const int l0 = tid * 8, l1 = 64 * 32 + tid * 8;

    const int fr  = lane & 15;               // row within 16-row fragment
    const int fkb = (lane >> 4) << 4;        // byte col of k-slice (0/16/32/48)
    const int swz = ((fr >> 1) & 3) << 4;    // row-dependent XOR (row%16 == fr)

    f32x4 acc[4][4] = {};

    for (int kt = 0; kt < kK / 32; ++kt) {
        const int kk = kt * 32;              // element offset along K
        __syncthreads();
        GLL(Ah + rA + kk, sAh + l0);  GLL(Ah + rA1 + kk, sAh + l1);
        GLL(Am + rA + kk, sAm + l0);  GLL(Am + rA1 + kk, sAm + l1);
        GLL(Al + rA + kk, sAl + l0);  GLL(Al + rA1 + kk, sAl + l1);
        GLL(Bh + rB + kk, sBh + l0);  GLL(Bh + rB1 + kk, sBh + l1);
        GLL(Bm + rB + kk, sBm + l0);  GLL(Bm + rB1 + kk, sBm + l1);
        GLL(Bl + rB + kk, sBl + l0);  GLL(Bl + rB1 + kk, sBl + l1);
        __syncthreads();

        bf16x8 ah[4], am[4], al[4], bh[4], bmf[4], bl[4];
#pragma unroll
        for (int mi = 0; mi < 4; ++mi) {
            int row = wr * 64 + mi * 16 + fr;
            int off = row * 64 + (fkb ^ swz);
            ah[mi] = *(const bf16x8*)((const char*)sAh + off);
            am[mi] = *(const bf16x8*)((const char*)sAm + off);
            al[mi] = *(const bf16x8*)((const char*)sAl + off);
        }
#pragma unroll
        for (int ni = 0; ni < 4; ++ni) {
            int row = wc * 64 + ni * 16 + fr;
            int off = row * 64 + (fkb ^ swz);
            bh[ni]  = *(const bf16x8*)((const char*)sBh + off);
            bmf[ni] = *(const bf16x8*)((const char*)sBm + off);
            bl[ni]  = *(const bf16x8*)((const char*)sBl + off);
        }
#pragma unroll
        for (int mi = 0; mi < 4; ++mi)
#pragma unroll
            for (int ni = 0; ni < 4; ++ni) {
                f32x4 c = acc[mi][ni];
                c = __builtin_amdgcn_mfma_f32_16x16x32_bf16(ah[mi], bh[ni],  c, 0, 0, 0);
                c = __builtin_amdgcn_mfma_f32_16x16x32_bf16(ah[mi], bmf[ni], c, 0, 0, 0);
                c = __builtin_amdgcn_mfma_f32_16x16x32_bf16(am[mi], bh[ni],  c, 0, 0, 0);
                c = __builtin_amdgcn_mfma_f32_16x16x32_bf16(ah[mi], bl[ni],  c, 0, 0, 0);
                c = __builtin_amdgcn_mfma_f32_16x16x32_bf16(al[mi], bh[ni],  c, 0, 0, 0);
                c = __builtin_amdgcn_mfma_f32_16x16x32_bf16(am[mi], bmf[ni], c, 0, 0, 0);
                acc[mi][ni] = c;
            }
    }

    // epilogue: C/D layout col=lane&15, row=(lane>>4)*4+r   [m89-verified]
    const int col = lane & 15;
    const int rb  = (lane >> 4) << 2;
#pragma unroll
    for (int mi = 0; mi < 4; ++mi)
#pragma unroll
        for (int ni = 0; ni < 4; ++ni) {
            int n = bn * 128 + wc * 64 + ni * 16 + col;
#pragma unroll
            for (int r = 0; r < 4; ++r) {
                int m = bm * 128 + wr * 64 + mi * 16 + rb + r;
                P[(size_t)m * kN + n] = acc[mi][ni][r];
            }
        }
}

// ---- gather v3: 4x4 atom-group blocking, t split over 2 blocks -----------
// block = (b, th, gi, gj): 16 edges, 32 t-slots. 1024 blocks = 4/CU for
// latency hiding. b = bid&7 pins each batch's P slice (4MB) to the XCD that
// produced it; nontemporal output stores keep P L2-resident.
__global__ __launch_bounds__(256) void k_gather2(const float* __restrict__ P,
                                                 const float* __restrict__ bias,
                                                 const int* __restrict__ ij2e,
                                                 float* __restrict__ out) {
    const int bid = blockIdx.x;              // 0..1023
    const int b  = bid & 7;
    const int th = (bid >> 3) & 1;
    const int gi = (bid >> 4) & 7;
    const int gj = bid >> 7;
    __shared__ int se[16];
    if (threadIdx.x < 16) {
        int si = threadIdx.x >> 2, rj = threadIdx.x & 3;
        int i = gi * 4 + si, j = gj * 4 + rj;
        se[threadIdx.x] = (i == j) ? -1 : ij2e[i * kA + j];
    }
    __syncthreads();
    int e[16];
#pragma unroll
    for (int k = 0; k < 16; ++k) e[k] = se[k];

    const int c  = threadIdx.x & 63;         // f32x4 col 0..63
    const int t0 = th * 32 + (threadIdx.x >> 6);
    f32x4 bv = ((const f32x4*)bias)[c];
    const float* Pb = P + (size_t)(b * kA) * kT * kN;
    float* outb = out + (size_t)b * kE * kT * kNE;

    for (int t = t0; t < th * 32 + 32; t += 4) {
        f32x4 ps[4], pr[4];
#pragma unroll
        for (int si = 0; si < 4; ++si)
            ps[si] = *(const f32x4*)(Pb + ((size_t)(gi * 4 + si) * kT + t) * kN + c * 4);
#pragma unroll
        for (int rj = 0; rj < 4; ++rj)
            pr[rj] = *(const f32x4*)(Pb + ((size_t)(gj * 4 + rj) * kT + t) * kN + kNE + c * 4);
#pragma unroll
        for (int si = 0; si < 4; ++si)
#pragma unroll
            for (int rj = 0; rj < 4; ++rj) {
                int ee = e[si * 4 + rj];
                if (ee >= 0) {
                    f32x4 v = ps[si] + pr[rj] + bv;
                    __builtin_nontemporal_store(
                        v, (f32x4*)(outb + ((size_t)ee * kT + t) * kNE + c * 4));
                }
            }
    }
}

extern "C" void kernel_launch(void* const* d_in, const int* in_sizes, int n_in,
                              void* d_out, int out_size, void* d_ws, size_t ws_size,
                              hipStream_t stream) {
    const float* h    = (const float*)d_in[0];
    const float* rrec = (const float*)d_in[1];
    const float* rsnd = (const float*)d_in[2];
    const float* W    = (const float*)d_in[3];
    const float* bias = (const float*)d_in[4];
    float* out = (float*)d_out;

    char* ws = (char*)d_ws;
    const size_t MB = 1024 * 1024;
    unsigned short* Ah = (unsigned short*)(ws);                  // 8 MB
    unsigned short* Am = (unsigned short*)(ws + 8 * MB);         // 8 MB
    unsigned short* Al = (unsigned short*)(ws + 16 * MB);        // 8 MB
    unsigned short* Bh = (unsigned short*)(ws + 24 * MB);        // 256 KB
    unsigned short* Bm = (unsigned short*)(ws + 24 * MB + 256 * 1024);
    unsigned short* Bl = (unsigned short*)(ws + 24 * MB + 512 * 1024);
    float* P   = (float*)(ws + 25 * MB);                         // 32 MB
    int* ij2e  = (int*)(ws + 57 * MB);                           // 4 KB

    k_split_all<<<dim3(4096 + 128), dim3(256), 0, stream>>>(h, Ah, Am, Al,
                                                            W, Bh, Bm, Bl,
                                                            rrec, rsnd, ij2e);
    k_gemm3    <<<dim3(512),        dim3(256), 0, stream>>>(Ah, Am, Al, Bh, Bm, Bl, P);
    k_gather2  <<<dim3(1024),       dim3(256), 0, stream>>>(P, bias, ij2e, out);
}

// Round 6
// 129.053 us; speedup vs baseline: 1.4470x; 1.0823x over previous
//
#include <hip/hip_runtime.h>
#include <hip/hip_bf16.h>

using f32x4  = __attribute__((ext_vector_type(4))) float;
using bf16x8 = __attribute__((ext_vector_type(8))) short;
using s16x4  = __attribute__((ext_vector_type(4))) short;

constexpr int kB  = 8;
constexpr int kA  = 32;
constexpr int kT  = 64;
constexpr int kNH = 256;
constexpr int kNE = 256;                 // NEMB
constexpr int kE  = kA * (kA - 1);       // 992
constexpr int kM  = kB * kA * kT;        // 16384 rows of h
constexpr int kK  = kNH;                 // 256
constexpr int kN  = 2 * kNE;             // 512 (Ps | Pr)

__device__ __forceinline__ unsigned short rne_bf16(float f) {
    unsigned int u = __float_as_uint(f);
    u += 0x7fffu + ((u >> 16) & 1u);
    return (unsigned short)(u >> 16);
}
__device__ __forceinline__ float bf16_f32(unsigned short h) {
    return __uint_as_float(((unsigned int)h) << 16);
}
// 2-way split: x ~= hi + mid (each bf16), residual <= 2^-18 |x|
__device__ __forceinline__ void split2(float x, unsigned short& h, unsigned short& m) {
    h = rne_bf16(x);
    float r1 = x - bf16_f32(h);
    m = rne_bf16(r1);
}

// ---- fused split: h -> Ah/Am ; W -> Bh/Bm (B^T form) ; edge LUT ----------
__global__ __launch_bounds__(256) void k_split_all(const float* __restrict__ hsrc,
                                                   unsigned short* __restrict__ a1,
                                                   unsigned short* __restrict__ a2,
                                                   const float* __restrict__ W,
                                                   unsigned short* __restrict__ b1,
                                                   unsigned short* __restrict__ b2,
                                                   const float* __restrict__ rel_rec,
                                                   const float* __restrict__ rel_send,
                                                   int* __restrict__ ij2e) {
    const int bidx = blockIdx.x;
    if (bidx < 4096) {                                  // h: 16384*256 elems / 4
        int idx = bidx * 256 + threadIdx.x;
        f32x4 v = ((const f32x4*)hsrc)[idx];
        s16x4 o1, o2;
#pragma unroll
        for (int j = 0; j < 4; ++j) {
            unsigned short h, m;
            split2(v[j], h, m);
            o1[j] = (short)h; o2[j] = (short)m;
        }
        *(s16x4*)(a1 + (size_t)idx * 4) = o1;
        *(s16x4*)(a2 + (size_t)idx * 4) = o2;
        return;
    }
    const int wb  = bidx - 4096;                        // 0..127
    int idx = wb * 256 + threadIdx.x;                   // per 4 elems; 32768 total
    int n  = idx >> 6;                                  // 0..511
    int k4 = (idx & 63) << 2;                           // 0..252
    const float* s = (n < kNE) ? (W + (size_t)n * (2 * kNH) + k4)
                               : (W + (size_t)(n - kNE) * (2 * kNH) + kNH + k4);
    f32x4 v = *(const f32x4*)s;
    s16x4 o1, o2;
#pragma unroll
    for (int j = 0; j < 4; ++j) {
        unsigned short h, m;
        split2(v[j], h, m);
        o1[j] = (short)h; o2[j] = (short)m;
    }
    size_t off = (size_t)n * kK + k4;
    *(s16x4*)(b1 + off) = o1;
    *(s16x4*)(b2 + off) = o2;

    // inverse edge LUT: ij2e[send*32 + recv] = e  (first 4 W-blocks)
    if (wb < 4) {
        int e = wb * 256 + threadIdx.x;
        if (e < kE) {
            int ir = 0, is = 0;
            for (int a = 0; a < kA; ++a) {
                if (rel_rec[(size_t)e * kA + a]  > 0.5f) ir = a;
                if (rel_send[(size_t)e * kA + a] > 0.5f) is = a;
            }
            ij2e[is * kA + ir] = e;
        }
    }
}

// ---- GEMM: P[16384][512] = A[16384][256] * Bcat[512][256]^T, split-f32 ---
// 128x128 tile, BK=32 (64B rows), 4 waves (2x2), 4 MFMA terms per frag pair:
//   ah*bh + ah*bm + am*bh + am*bm    (dropped mass <= 2^-17 * sum|h||w|)
// Swizzle: XOR byte-col with ((row>>1)&3)<<4 — in-row (64B), 2-way conflicts
// (free). Same XOR on pre-swizzled global source (involution, rule #21).
// Decode: xcd=bid&7 pins batch b=xcd to its XCD (L2 locality for gather);
// bn=(bid>>3)&3 varies fastest within an XCD for A-panel L2 reuse.
#define GLL(g, l) __builtin_amdgcn_global_load_lds( \
    (const __attribute__((address_space(1))) void*)(g), \
    (__attribute__((address_space(3))) void*)(l), 16, 0, 0)

__global__ __launch_bounds__(256) void k_gemm4(const unsigned short* __restrict__ Ah,
                                               const unsigned short* __restrict__ Am,
                                               const unsigned short* __restrict__ Bh,
                                               const unsigned short* __restrict__ Bm,
                                               float* __restrict__ P) {
    __shared__ unsigned short sAh[128 * 32], sAm[128 * 32];
    __shared__ unsigned short sBh[128 * 32], sBm[128 * 32];
    const int tid  = threadIdx.x;
    const int lane = tid & 63;
    const int wave = tid >> 6;
    const int wr = wave >> 1, wc = wave & 1;
    const int bid = blockIdx.x;                     // 0..511
    const int xcd = bid & 7;
    const int idx = bid >> 3;                       // 0..63
    const int bn  = idx & 3;                        // fastest within XCD
    const int bm  = xcd * 16 + (idx >> 2);          // batch b = xcd

    // staging: thread tid covers LDS bytes [tid*16, tid*16+16) of a 64-row half-tile
    const int sr   = tid >> 2;                      // row within half-tile (0..63)
    const int scb  = (tid & 3) << 4;                // byte col within 64B row
    const int scbs = scb ^ (((sr >> 1) & 3) << 4);  // pre-swizzled source col, in [0,64)
    const size_t rA  = (size_t)(bm * 128 + sr) * kK + (scbs >> 1);
    const size_t rB  = (size_t)(bn * 128 + sr) * kK + (scbs >> 1);
    const size_t rA1 = rA + (size_t)64 * kK;
    const size_t rB1 = rB + (size_t)64 * kK;
    const int l0 = tid * 8, l1 = 64 * 32 + tid * 8;

    const int fr  = lane & 15;               // row within 16-row fragment
    const int fkb = (lane >> 4) << 4;        // byte col of k-slice (0/16/32/48)
    const int swz = ((fr >> 1) & 3) << 4;    // row-dependent XOR (row%16 == fr)

    f32x4 acc[4][4] = {};

    for (int kt = 0; kt < kK / 32; ++kt) {
        const int kk = kt * 32;              // element offset along K
        __syncthreads();
        GLL(Ah + rA + kk, sAh + l0);  GLL(Ah + rA1 + kk, sAh + l1);
        GLL(Am + rA + kk, sAm + l0);  GLL(Am + rA1 + kk, sAm + l1);
        GLL(Bh + rB + kk, sBh + l0);  GLL(Bh + rB1 + kk, sBh + l1);
        GLL(Bm + rB + kk, sBm + l0);  GLL(Bm + rB1 + kk, sBm + l1);
        __syncthreads();

        bf16x8 ah[4], am[4], bh[4], bmf[4];
#pragma unroll
        for (int mi = 0; mi < 4; ++mi) {
            int row = wr * 64 + mi * 16 + fr;
            int off = row * 64 + (fkb ^ swz);
            ah[mi] = *(const bf16x8*)((const char*)sAh + off);
            am[mi] = *(const bf16x8*)((const char*)sAm + off);
        }
#pragma unroll
        for (int ni = 0; ni < 4; ++ni) {
            int row = wc * 64 + ni * 16 + fr;
            int off = row * 64 + (fkb ^ swz);
            bh[ni]  = *(const bf16x8*)((const char*)sBh + off);
            bmf[ni] = *(const bf16x8*)((const char*)sBm + off);
        }
#pragma unroll
        for (int mi = 0; mi < 4; ++mi)
#pragma unroll
            for (int ni = 0; ni < 4; ++ni) {
                f32x4 c = acc[mi][ni];
                c = __builtin_amdgcn_mfma_f32_16x16x32_bf16(ah[mi], bh[ni],  c, 0, 0, 0);
                c = __builtin_amdgcn_mfma_f32_16x16x32_bf16(ah[mi], bmf[ni], c, 0, 0, 0);
                c = __builtin_amdgcn_mfma_f32_16x16x32_bf16(am[mi], bh[ni],  c, 0, 0, 0);
                c = __builtin_amdgcn_mfma_f32_16x16x32_bf16(am[mi], bmf[ni], c, 0, 0, 0);
                acc[mi][ni] = c;
            }
    }

    // epilogue: C/D layout col=lane&15, row=(lane>>4)*4+r   [m89-verified]
    const int col = lane & 15;
    const int rb  = (lane >> 4) << 2;
#pragma unroll
    for (int mi = 0; mi < 4; ++mi)
#pragma unroll
        for (int ni = 0; ni < 4; ++ni) {
            int n = bn * 128 + wc * 64 + ni * 16 + col;
#pragma unroll
            for (int r = 0; r < 4; ++r) {
                int m = bm * 128 + wr * 64 + mi * 16 + rb + r;
                P[(size_t)m * kN + n] = acc[mi][ni][r];
            }
        }
}

// ---- gather: 4x4 atom-group blocking, t split over 2 blocks --------------
// block = (b, th, gi, gj): 16 edges, 32 t-slots. 1024 blocks = 4/CU.
// b = bid&7 pins each batch's P slice (4MB) to the XCD that produced it;
// nontemporal output stores keep P L2-resident.
__global__ __launch_bounds__(256) void k_gather2(const float* __restrict__ P,
                                                 const float* __restrict__ bias,
                                                 const int* __restrict__ ij2e,
                                                 float* __restrict__ out) {
    const int bid = blockIdx.x;              // 0..1023
    const int b  = bid & 7;
    const int th = (bid >> 3) & 1;
    const int gi = (bid >> 4) & 7;
    const int gj = bid >> 7;
    __shared__ int se[16];
    if (threadIdx.x < 16) {
        int si = threadIdx.x >> 2, rj = threadIdx.x & 3;
        int i = gi * 4 + si, j = gj * 4 + rj;
        se[threadIdx.x] = (i == j) ? -1 : ij2e[i * kA + j];
    }
    __syncthreads();
    int e[16];
#pragma unroll
    for (int k = 0; k < 16; ++k) e[k] = se[k];

    const int c  = threadIdx.x & 63;         // f32x4 col 0..63
    const int t0 = th * 32 + (threadIdx.x >> 6);
    f32x4 bv = ((const f32x4*)bias)[c];
    const float* Pb = P + (size_t)(b * kA) * kT * kN;
    float* outb = out + (size_t)b * kE * kT * kNE;

    for (int t = t0; t < th * 32 + 32; t += 4) {
        f32x4 ps[4], pr[4];
#pragma unroll
        for (int si = 0; si < 4; ++si)
            ps[si] = *(const f32x4*)(Pb + ((size_t)(gi * 4 + si) * kT + t) * kN + c * 4);
#pragma unroll
        for (int rj = 0; rj < 4; ++rj)
            pr[rj] = *(const f32x4*)(Pb + ((size_t)(gj * 4 + rj) * kT + t) * kN + kNE + c * 4);
#pragma unroll
        for (int si = 0; si < 4; ++si)
#pragma unroll
            for (int rj = 0; rj < 4; ++rj) {
                int ee = e[si * 4 + rj];
                if (ee >= 0) {
                    f32x4 v = ps[si] + pr[rj] + bv;
                    __builtin_nontemporal_store(
                        v, (f32x4*)(outb + ((size_t)ee * kT + t) * kNE + c * 4));
                }
            }
    }
}

extern "C" void kernel_launch(void* const* d_in, const int* in_sizes, int n_in,
                              void* d_out, int out_size, void* d_ws, size_t ws_size,
                              hipStream_t stream) {
    const float* h    = (const float*)d_in[0];
    const float* rrec = (const float*)d_in[1];
    const float* rsnd = (const float*)d_in[2];
    const float* W    = (const float*)d_in[3];
    const float* bias = (const float*)d_in[4];
    float* out = (float*)d_out;

    char* ws = (char*)d_ws;
    const size_t MB = 1024 * 1024;
    unsigned short* Ah = (unsigned short*)(ws);                  // 8 MB
    unsigned short* Am = (unsigned short*)(ws + 8 * MB);         // 8 MB
    unsigned short* Bh = (unsigned short*)(ws + 16 * MB);        // 256 KB
    unsigned short* Bm = (unsigned short*)(ws + 16 * MB + 256 * 1024);
    float* P   = (float*)(ws + 17 * MB);                         // 32 MB
    int* ij2e  = (int*)(ws + 49 * MB);                           // 4 KB

    k_split_all<<<dim3(4096 + 128), dim3(256), 0, stream>>>(h, Ah, Am,
                                                            W, Bh, Bm,
                                                            rrec, rsnd, ij2e);
    k_gemm4    <<<dim3(512),        dim3(256), 0, stream>>>(Ah, Am, Bh, Bm, P);
    k_gather2  <<<dim3(1024),       dim3(256), 0, stream>>>(P, bias, ij2e, out);
}

// Round 7
// 128.402 us; speedup vs baseline: 1.4544x; 1.0051x over previous
//
#include <hip/hip_runtime.h>
#include <hip/hip_bf16.h>

using f32x4  = __attribute__((ext_vector_type(4))) float;
using bf16x8 = __attribute__((ext_vector_type(8))) short;
using s16x4  = __attribute__((ext_vector_type(4))) short;

constexpr int kB  = 8;
constexpr int kA  = 32;
constexpr int kT  = 64;
constexpr int kNH = 256;
constexpr int kNE = 256;                 // NEMB
constexpr int kE  = kA * (kA - 1);       // 992
constexpr int kM  = kB * kA * kT;        // 16384 rows of h
constexpr int kK  = kNH;                 // 256
constexpr int kN  = 2 * kNE;             // 512 (Ps | Pr)

__device__ __forceinline__ unsigned short rne_bf16(float f) {
    unsigned int u = __float_as_uint(f);
    u += 0x7fffu + ((u >> 16) & 1u);
    return (unsigned short)(u >> 16);
}
__device__ __forceinline__ float bf16_f32(unsigned short h) {
    return __uint_as_float(((unsigned int)h) << 16);
}
// 2-way split: x ~= hi + mid (each bf16), residual <= 2^-17 |x|
__device__ __forceinline__ void split2(float x, unsigned short& h, unsigned short& m) {
    h = rne_bf16(x);
    float r1 = x - bf16_f32(h);
    m = rne_bf16(r1);
}

// ---- fused split: h -> Ah/Am ; W -> Bh/Bm (B^T form) ; edge LUT ----------
__global__ __launch_bounds__(256) void k_split_all(const float* __restrict__ hsrc,
                                                   unsigned short* __restrict__ a1,
                                                   unsigned short* __restrict__ a2,
                                                   const float* __restrict__ W,
                                                   unsigned short* __restrict__ b1,
                                                   unsigned short* __restrict__ b2,
                                                   const float* __restrict__ rel_rec,
                                                   const float* __restrict__ rel_send,
                                                   int* __restrict__ ij2e) {
    const int bidx = blockIdx.x;
    if (bidx < 4096) {                                  // h: 16384*256 elems / 4
        int idx = bidx * 256 + threadIdx.x;
        f32x4 v = ((const f32x4*)hsrc)[idx];
        s16x4 o1, o2;
#pragma unroll
        for (int j = 0; j < 4; ++j) {
            unsigned short h, m;
            split2(v[j], h, m);
            o1[j] = (short)h; o2[j] = (short)m;
        }
        *(s16x4*)(a1 + (size_t)idx * 4) = o1;
        *(s16x4*)(a2 + (size_t)idx * 4) = o2;
        return;
    }
    const int wb  = bidx - 4096;                        // 0..127
    int idx = wb * 256 + threadIdx.x;                   // per 4 elems; 32768 total
    int n  = idx >> 6;                                  // 0..511
    int k4 = (idx & 63) << 2;                           // 0..252
    const float* s = (n < kNE) ? (W + (size_t)n * (2 * kNH) + k4)
                               : (W + (size_t)(n - kNE) * (2 * kNH) + kNH + k4);
    f32x4 v = *(const f32x4*)s;
    s16x4 o1, o2;
#pragma unroll
    for (int j = 0; j < 4; ++j) {
        unsigned short h, m;
        split2(v[j], h, m);
        o1[j] = (short)h; o2[j] = (short)m;
    }
    size_t off = (size_t)n * kK + k4;
    *(s16x4*)(b1 + off) = o1;
    *(s16x4*)(b2 + off) = o2;

    // inverse edge LUT: ij2e[send*32 + recv] = e  (first 4 W-blocks)
    if (wb < 4) {
        int e = wb * 256 + threadIdx.x;
        if (e < kE) {
            int ir = 0, is = 0;
            for (int a = 0; a < kA; ++a) {
                if (rel_rec[(size_t)e * kA + a]  > 0.5f) ir = a;
                if (rel_send[(size_t)e * kA + a] > 0.5f) is = a;
            }
            ij2e[is * kA + ir] = e;
        }
    }
}

// ---- GEMM: P[16384][512] = A[16384][256] * Bcat[512][256]^T, split-f32 ---
// 128x128 tile, BK=32 (64B rows), 4 waves (2x2), 3 MFMA terms per frag pair:
//   ah*bh + ah*bm + am*bh      (dropped am*bm <= 2^-16 * sum|a||b| ~ 0.02)
// T3-minimum 2-phase pipeline: double-buffered LDS; per k-tile the NEXT
// tile's global_load_lds is issued BEFORE the current tile's ds_read+MFMA,
// so the __syncthreads() vmcnt-drain lands after compute has covered the
// load latency (was: serial stage->drain->compute each tile).
// Swizzle: XOR byte-col with ((row>>1)&3)<<4 — in-row (64B), 2-way (free);
// same XOR on pre-swizzled global source (involution, rule #21).
// Decode: xcd=bid&7 pins batch b=xcd to its XCD (gather L2 locality);
// bn=(bid>>3)&3 fastest within an XCD for A-panel L2 reuse.
#define GLL(g, l) __builtin_amdgcn_global_load_lds( \
    (const __attribute__((address_space(1))) void*)(g), \
    (__attribute__((address_space(3))) void*)(l), 16, 0, 0)

__global__ __launch_bounds__(256) void k_gemm5(const unsigned short* __restrict__ Ah,
                                               const unsigned short* __restrict__ Am,
                                               const unsigned short* __restrict__ Bh,
                                               const unsigned short* __restrict__ Bm,
                                               float* __restrict__ P) {
    __shared__ unsigned short sAh[2][128 * 32], sAm[2][128 * 32];
    __shared__ unsigned short sBh[2][128 * 32], sBm[2][128 * 32];
    const int tid  = threadIdx.x;
    const int lane = tid & 63;
    const int wave = tid >> 6;
    const int wr = wave >> 1, wc = wave & 1;
    const int bid = blockIdx.x;                     // 0..511
    const int xcd = bid & 7;
    const int idx = bid >> 3;                       // 0..63
    const int bn  = idx & 3;                        // fastest within XCD
    const int bm  = xcd * 16 + (idx >> 2);          // batch b = xcd

    // staging: thread tid covers LDS bytes [tid*16, tid*16+16) of a 64-row half-tile
    const int sr   = tid >> 2;                      // row within half-tile (0..63)
    const int scb  = (tid & 3) << 4;                // byte col within 64B row
    const int scbs = scb ^ (((sr >> 1) & 3) << 4);  // pre-swizzled source col, in [0,64)
    const size_t rA  = (size_t)(bm * 128 + sr) * kK + (scbs >> 1);
    const size_t rB  = (size_t)(bn * 128 + sr) * kK + (scbs >> 1);
    const size_t rA1 = rA + (size_t)64 * kK;
    const size_t rB1 = rB + (size_t)64 * kK;
    const int l0 = tid * 8, l1 = 64 * 32 + tid * 8;

    const int fr  = lane & 15;               // row within 16-row fragment
    const int fkb = (lane >> 4) << 4;        // byte col of k-slice (0/16/32/48)
    const int swz = ((fr >> 1) & 3) << 4;    // row-dependent XOR (row%16 == fr)

    f32x4 acc[4][4] = {};

#define STAGE(buf, kk)                                                        \
    do {                                                                      \
        GLL(Ah + rA + (kk), sAh[buf] + l0);  GLL(Ah + rA1 + (kk), sAh[buf] + l1); \
        GLL(Am + rA + (kk), sAm[buf] + l0);  GLL(Am + rA1 + (kk), sAm[buf] + l1); \
        GLL(Bh + rB + (kk), sBh[buf] + l0);  GLL(Bh + rB1 + (kk), sBh[buf] + l1); \
        GLL(Bm + rB + (kk), sBm[buf] + l0);  GLL(Bm + rB1 + (kk), sBm[buf] + l1); \
    } while (0)

    STAGE(0, 0);
    __syncthreads();                         // drain prologue loads

#pragma unroll
    for (int kt = 0; kt < 8; ++kt) {
        const int cur = kt & 1;
        if (kt < 7) STAGE(cur ^ 1, (kt + 1) * 32);   // prefetch next tile

        bf16x8 ah[4], am[4], bh[4], bmf[4];
#pragma unroll
        for (int mi = 0; mi < 4; ++mi) {
            int row = wr * 64 + mi * 16 + fr;
            int off = row * 64 + (fkb ^ swz);
            ah[mi] = *(const bf16x8*)((const char*)sAh[cur] + off);
            am[mi] = *(const bf16x8*)((const char*)sAm[cur] + off);
        }
#pragma unroll
        for (int ni = 0; ni < 4; ++ni) {
            int row = wc * 64 + ni * 16 + fr;
            int off = row * 64 + (fkb ^ swz);
            bh[ni]  = *(const bf16x8*)((const char*)sBh[cur] + off);
            bmf[ni] = *(const bf16x8*)((const char*)sBm[cur] + off);
        }
#pragma unroll
        for (int mi = 0; mi < 4; ++mi)
#pragma unroll
            for (int ni = 0; ni < 4; ++ni) {
                f32x4 c = acc[mi][ni];
                c = __builtin_amdgcn_mfma_f32_16x16x32_bf16(ah[mi], bh[ni],  c, 0, 0, 0);
                c = __builtin_amdgcn_mfma_f32_16x16x32_bf16(ah[mi], bmf[ni], c, 0, 0, 0);
                c = __builtin_amdgcn_mfma_f32_16x16x32_bf16(am[mi], bh[ni],  c, 0, 0, 0);
                acc[mi][ni] = c;
            }
        __syncthreads();                     // drain prefetch + LDS handoff
    }
#undef STAGE

    // epilogue: C/D layout col=lane&15, row=(lane>>4)*4+r   [m89-verified]
    const int col = lane & 15;
    const int rb  = (lane >> 4) << 2;
#pragma unroll
    for (int mi = 0; mi < 4; ++mi)
#pragma unroll
        for (int ni = 0; ni < 4; ++ni) {
            int n = bn * 128 + wc * 64 + ni * 16 + col;
#pragma unroll
            for (int r = 0; r < 4; ++r) {
                int m = bm * 128 + wr * 64 + mi * 16 + rb + r;
                P[(size_t)m * kN + n] = acc[mi][ni][r];
            }
        }
}

// ---- gather: 4x4 atom-group blocking, t split over 2 blocks --------------
// block = (b, th, gi, gj): 16 edges, 32 t-slots. 1024 blocks = 4/CU.
// b = bid&7 pins each batch's P slice (4MB) to the XCD that produced it;
// nontemporal output stores keep P L2-resident.
__global__ __launch_bounds__(256) void k_gather2(const float* __restrict__ P,
                                                 const float* __restrict__ bias,
                                                 const int* __restrict__ ij2e,
                                                 float* __restrict__ out) {
    const int bid = blockIdx.x;              // 0..1023
    const int b  = bid & 7;
    const int th = (bid >> 3) & 1;
    const int gi = (bid >> 4) & 7;
    const int gj = bid >> 7;
    __shared__ int se[16];
    if (threadIdx.x < 16) {
        int si = threadIdx.x >> 2, rj = threadIdx.x & 3;
        int i = gi * 4 + si, j = gj * 4 + rj;
        se[threadIdx.x] = (i == j) ? -1 : ij2e[i * kA + j];
    }
    __syncthreads();
    int e[16];
#pragma unroll
    for (int k = 0; k < 16; ++k) e[k] = se[k];

    const int c  = threadIdx.x & 63;         // f32x4 col 0..63
    const int t0 = th * 32 + (threadIdx.x >> 6);
    f32x4 bv = ((const f32x4*)bias)[c];
    const float* Pb = P + (size_t)(b * kA) * kT * kN;
    float* outb = out + (size_t)b * kE * kT * kNE;

    for (int t = t0; t < th * 32 + 32; t += 4) {
        f32x4 ps[4], pr[4];
#pragma unroll
        for (int si = 0; si < 4; ++si)
            ps[si] = *(const f32x4*)(Pb + ((size_t)(gi * 4 + si) * kT + t) * kN + c * 4);
#pragma unroll
        for (int rj = 0; rj < 4; ++rj)
            pr[rj] = *(const f32x4*)(Pb + ((size_t)(gj * 4 + rj) * kT + t) * kN + kNE + c * 4);
#pragma unroll
        for (int si = 0; si < 4; ++si)
#pragma unroll
            for (int rj = 0; rj < 4; ++rj) {
                int ee = e[si * 4 + rj];
                if (ee >= 0) {
                    f32x4 v = ps[si] + pr[rj] + bv;
                    __builtin_nontemporal_store(
                        v, (f32x4*)(outb + ((size_t)ee * kT + t) * kNE + c * 4));
                }
            }
    }
}

extern "C" void kernel_launch(void* const* d_in, const int* in_sizes, int n_in,
                              void* d_out, int out_size, void* d_ws, size_t ws_size,
                              hipStream_t stream) {
    const float* h    = (const float*)d_in[0];
    const float* rrec = (const float*)d_in[1];
    const float* rsnd = (const float*)d_in[2];
    const float* W    = (const float*)d_in[3];
    const float* bias = (const float*)d_in[4];
    float* out = (float*)d_out;

    char* ws = (char*)d_ws;
    const size_t MB = 1024 * 1024;
    unsigned short* Ah = (unsigned short*)(ws);                  // 8 MB
    unsigned short* Am = (unsigned short*)(ws + 8 * MB);         // 8 MB
    unsigned short* Bh = (unsigned short*)(ws + 16 * MB);        // 256 KB
    unsigned short* Bm = (unsigned short*)(ws + 16 * MB + 256 * 1024);
    float* P   = (float*)(ws + 17 * MB);                         // 32 MB
    int* ij2e  = (int*)(ws + 49 * MB);                           // 4 KB

    k_split_all<<<dim3(4096 + 128), dim3(256), 0, stream>>>(h, Ah, Am,
                                                            W, Bh, Bm,
                                                            rrec, rsnd, ij2e);
    k_gemm5    <<<dim3(512),        dim3(256), 0, stream>>>(Ah, Am, Bh, Bm, P);
    k_gather2  <<<dim3(1024),       dim3(256), 0, stream>>>(P, bias, ij2e, out);
}